// Round 1
// baseline (610.233 us; speedup 1.0000x reference)
//
#include <hip/hip_runtime.h>
#include <cstdint>
#include <cstddef>

// Problem constants (from reference)
#define N_TOK 4096
#define K_DIM 4096
#define M_DIM 12288

using i32x4 = __attribute__((ext_vector_type(4))) int;

// ---------------- pack int32 -> int8 ----------------
// x: N*K ints -> 16 MB int8 ; w: M*K ints -> 48 MB int8 (both into d_ws)
constexpr long CHUNKS_X = ((long)N_TOK * K_DIM) / 16;   // 1,048,576
constexpr long CHUNKS_W = ((long)M_DIM * K_DIM) / 16;   // 3,145,728
constexpr long CHUNKS_TOTAL = CHUNKS_X + CHUNKS_W;      // 4,194,304

__global__ __launch_bounds__(256) void pack_i8_kernel(
    const int* __restrict__ x, const int* __restrict__ w,
    int8_t* __restrict__ x8, int8_t* __restrict__ w8)
{
  long idx = (long)blockIdx.x * 256 + threadIdx.x;  // one thread per 16 elems
  const int* src;
  int8_t* dst;
  if (idx < CHUNKS_X) { src = x + idx * 16; dst = x8 + idx * 16; }
  else { long j = idx - CHUNKS_X; src = w + j * 16; dst = w8 + j * 16; }
  i32x4 v0 = *(const i32x4*)(src);
  i32x4 v1 = *(const i32x4*)(src + 4);
  i32x4 v2 = *(const i32x4*)(src + 8);
  i32x4 v3 = *(const i32x4*)(src + 12);
  auto pack4 = [](i32x4 v) -> int {
    return (int)((unsigned)(v.x & 0xff)        | ((unsigned)(v.y & 0xff) << 8) |
                 ((unsigned)(v.z & 0xff) << 16) | ((unsigned)(v.w & 0xff) << 24));
  };
  i32x4 o;
  o.x = pack4(v0); o.y = pack4(v1); o.z = pack4(v2); o.w = pack4(v3);
  *(i32x4*)dst = o;
}

// ---------------- i8 GEMM with fused dequant epilogue ----------------
#define BM 128
#define BN 128
#define BK 128                      // i8 elements (= bytes) per K-tile
#define GRID_M (N_TOK / BM)         // 32
#define GRID_N (M_DIM / BN)         // 96
#define NWG (GRID_M * GRID_N)       // 3072
#define KT (K_DIM / BK)             // 32

__device__ __forceinline__ void load_lds16(const void* g, void* l) {
  __builtin_amdgcn_global_load_lds(
      (const __attribute__((address_space(1))) void*)g,
      (__attribute__((address_space(3))) void*)l, 16, 0, 0);
}

__global__ __launch_bounds__(256, 2) void w8a8_gemm_kernel(
    const int8_t* __restrict__ A8,            // [N_TOK][K_DIM]
    const int8_t* __restrict__ B8,            // [M_DIM][K_DIM]  (row = out col)
    const float* __restrict__ input_scale,    // [N_TOK]
    const float* __restrict__ dequant_scale,  // [M_DIM]
    const float* __restrict__ bias,           // [M_DIM]
    float* __restrict__ out)                  // [N_TOK][M_DIM] f32
{
  // LDS: double-buffered 128x128 i8 tiles for A and B. 64 KB total -> 2 blocks/CU.
  __shared__ int8_t As[2][BM * BK];
  __shared__ int8_t Bs[2][BN * BK];

  const int tid  = threadIdx.x;
  const int lane = tid & 63;
  const int wid  = tid >> 6;   // 0..3
  const int wr   = wid >> 1;   // wave row 0..1 (64 rows each)
  const int wc   = wid & 1;    // wave col 0..1 (64 cols each)
  const int lr   = lane & 15;  // fragment row (A) / col-of-C (B)
  const int lg   = lane >> 4;  // k-group 0..3
  const int xr   = (lr & 7) << 4;  // per-lane XOR for swizzled ds_read

  // Block swizzle: XCD chunking (3072 % 8 == 0 -> bijective) + GROUP_M=8
  int bid = blockIdx.x;
  int w_  = (bid & 7) * (NWG / 8) + (bid >> 3);
  const int GROUP = 8;
  const int width = GROUP * GRID_N;     // 768
  int gid = w_ / width;
  int rem = w_ % width;
  int bm  = gid * GROUP + (rem % GROUP);   // GRID_M % GROUP == 0, no tail
  int bn  = rem / GROUP;
  const int brow = bm * BM;
  const int bcol = bn * BN;

  // Stage one 128x128 i8 tile pair via global_load_lds (width 16).
  // LDS dest is LINEAR (base + lane*16, required by HW); the bank-conflict
  // swizzle slot' = slot ^ (row&7) is applied on the GLOBAL source address,
  // and the same XOR on the ds_read side (both-sides-or-neither rule).
  auto stage = [&](int buf, int kt) {
    const int k0 = kt * BK;
#pragma unroll
    for (int t = 0; t < 4; ++t) {
      int c = t * 256 + tid;                 // 16B chunk id, 1024 per tile
      int row = c >> 3;
      int slot = (c & 7) ^ (row & 7);
      load_lds16(A8 + (size_t)(brow + row) * K_DIM + k0 + slot * 16,
                 &As[buf][c * 16]);
    }
#pragma unroll
    for (int t = 0; t < 4; ++t) {
      int c = t * 256 + tid;
      int row = c >> 3;
      int slot = (c & 7) ^ (row & 7);
      load_lds16(B8 + (size_t)(bcol + row) * K_DIM + k0 + slot * 16,
                 &Bs[buf][c * 16]);
    }
  };

  i32x4 acc[4][4] = {};   // 16 fragments of 16x16, int32

  stage(0, 0);
  for (int kt = 0; kt < KT; ++kt) {
    const int cur = kt & 1;
    __syncthreads();                    // staging of buf[cur] complete
    if (kt + 1 < KT) stage(cur ^ 1, kt + 1);
#pragma unroll
    for (int s = 0; s < 2; ++s) {       // two K=64 steps per 128-tile
      i32x4 a[4], b[4];
#pragma unroll
      for (int i = 0; i < 4; ++i)
        a[i] = *(const i32x4*)&As[cur][(wr * 64 + i * 16 + lr) * BK +
                                       ((s * 64 + lg * 16) ^ xr)];
#pragma unroll
      for (int j = 0; j < 4; ++j)
        b[j] = *(const i32x4*)&Bs[cur][(wc * 64 + j * 16 + lr) * BK +
                                       ((s * 64 + lg * 16) ^ xr)];
#pragma unroll
      for (int i = 0; i < 4; ++i)
#pragma unroll
        for (int j = 0; j < 4; ++j)
          acc[i][j] = __builtin_amdgcn_mfma_i32_16x16x64_i8(a[i], b[j],
                                                            acc[i][j], 0, 0, 0);
    }
  }

  // Epilogue: out[n][m] = acc * is[n] * ds[m] + bias[m]
  // C/D layout (16x16): col = lane&15, row = (lane>>4)*4 + reg
  const int orow = brow + wr * 64;
  const int ocol = bcol + wc * 64 + lr;
  float isc[4][4];
#pragma unroll
  for (int i = 0; i < 4; ++i)
#pragma unroll
    for (int r = 0; r < 4; ++r)
      isc[i][r] = input_scale[orow + i * 16 + lg * 4 + r];

#pragma unroll
  for (int j = 0; j < 4; ++j) {
    const int m = ocol + j * 16;
    const float dsc = dequant_scale[m];
    const float bs  = bias[m];
#pragma unroll
    for (int i = 0; i < 4; ++i) {
#pragma unroll
      for (int r = 0; r < 4; ++r) {
        const int n = orow + i * 16 + lg * 4 + r;
        out[(size_t)n * M_DIM + m] = (float)acc[i][j][r] * isc[i][r] * dsc + bs;
      }
    }
  }
}

extern "C" void kernel_launch(void* const* d_in, const int* in_sizes, int n_in,
                              void* d_out, int out_size, void* d_ws, size_t ws_size,
                              hipStream_t stream) {
  const int*   x             = (const int*)d_in[0];     // [N,K] int32 (values fit i8)
  const int*   w             = (const int*)d_in[1];     // [M,K] int32
  const float* input_scale   = (const float*)d_in[2];   // [N]
  const float* dequant_scale = (const float*)d_in[3];   // [M]
  const float* bias          = (const float*)d_in[4];   // [M]
  float*       out           = (float*)d_out;           // [N,M] f32

  int8_t* x8 = (int8_t*)d_ws;                           // 16 MB
  int8_t* w8 = x8 + (size_t)N_TOK * K_DIM;              // 48 MB, 16MB-aligned

  pack_i8_kernel<<<(int)(CHUNKS_TOTAL / 256), 256, 0, stream>>>(x, w, x8, w8);
  w8a8_gemm_kernel<<<NWG, 256, 0, stream>>>(x8, w8, input_scale, dequant_scale,
                                            bias, out);
}

// Round 2
// 567.880 us; speedup vs baseline: 1.0746x; 1.0746x over previous
//
#include <hip/hip_runtime.h>
#include <cstdint>
#include <cstddef>

// Problem constants (from reference)
#define N_TOK 4096
#define K_DIM 4096
#define M_DIM 12288

using i32x4 = __attribute__((ext_vector_type(4))) int;

// ---------------- pack int32 -> int8 (fully coalesced) ----------------
// Each thread: one 16-B load (4 ints, consecutive lanes consecutive addrs)
// -> pack to one dword -> one 4-B store. x8 and w8 are contiguous in d_ws,
// so the output is a single linear int array.
constexpr long GROUPS_X     = (long)N_TOK * K_DIM / 4;               // 4,194,304
constexpr long GROUPS_TOTAL = ((long)N_TOK + M_DIM) * K_DIM / 4;     // 16,777,216

__global__ __launch_bounds__(256) void pack_i8_kernel(
    const int* __restrict__ x, const int* __restrict__ w, int* __restrict__ out8)
{
  const long stride = (long)gridDim.x * 256;
  for (long g = (long)blockIdx.x * 256 + threadIdx.x; g < GROUPS_TOTAL; g += stride) {
    const int* src = (g < GROUPS_X) ? (x + g * 4) : (w + (g - GROUPS_X) * 4);
    i32x4 v = *(const i32x4*)src;
    out8[g] = (v.x & 0xff) | ((v.y & 0xff) << 8) | ((v.z & 0xff) << 16) | (v.w << 24);
  }
}

// ---------------- i8 GEMM, 256x256 8-phase pipeline ----------------
#define BM 256
#define BN 256
#define KT 32                        // K_DIM / 128 bytes per K-tile
#define GRID_M (N_TOK / BM)          // 16
#define GRID_N (M_DIM / BN)          // 48
#define NWG (GRID_M * GRID_N)        // 768

__device__ __forceinline__ void load_lds16(const void* g, void* l) {
  __builtin_amdgcn_global_load_lds(
      (const __attribute__((address_space(1))) void*)g,
      (__attribute__((address_space(3))) void*)l, 16, 0, 0);
}

// LDS map: region(buf, ab, s) = (buf*4 + ab*2 + s) * 16384 bytes.
// Each region: [256 rows][64 B] row-major, 16 KiB. Total 128 KiB.
// Swizzle (both-sides involution): 16-B slot' = slot ^ (row & 3).

// Stage one region (16 KiB) = 2 global_load_lds per thread (512 threads).
__device__ __forceinline__ void stage_region(
    int8_t* lds, int buf, int ab, int s, int ktarg,
    const int8_t* A8, const int8_t* B8, int brow, int bcol, int tid)
{
  const int8_t* gbase = ab ? (B8 + (size_t)bcol * K_DIM)
                           : (A8 + (size_t)brow * K_DIM);
  const int lb = (buf * 4 + ab * 2 + s) * 16384;
  const int gk = ktarg * 128 + s * 64;
#pragma unroll
  for (int p = 0; p < 2; ++p) {
    int c = p * 512 + tid;           // 0..1023 chunks of 16 B
    int row  = c >> 2;
    int slot = (c & 3) ^ (row & 3);  // inverse-swizzled GLOBAL source
    load_lds16(gbase + (size_t)row * K_DIM + gk + slot * 16,
               lds + lb + c * 16);   // LINEAR LDS dest (HW requirement)
  }
}

// One K-tile = 4 phases. MODE: 2 = stage kt+1.k1 and kt+2.k0 (steady),
// 1 = stage only kt+1.k1 (kt == KT-2), 0 = no staging (last K-tile).
template <int MODE>
__device__ __forceinline__ void ktile(
    int kt, int8_t* lds, const int8_t* A8, const int8_t* B8,
    int brow, int bcol, int tid, int wr, int wc, int lr, int xs16,
    i32x4 (&acc)[8][4])
{
  const int cur = kt & 1;
  const int bA0 = (cur * 4 + 0) * 16384;
  const int bA1 = (cur * 4 + 1) * 16384;
  const int bB0 = (cur * 4 + 2) * 16384;
  const int bB1 = (cur * 4 + 3) * 16384;
  const int arow = wr * 128 + lr;    // A frag base row within tile
  const int bcol_ = wc * 64 + lr;    // B frag base row (output col) within tile

  i32x4 b[4];

  // ---- phase (s=0, h=0): read B.k0 + A.k0 rows 0-3; stage A of kt+1.k1 ----
  {
#pragma unroll
    for (int j = 0; j < 4; ++j)
      b[j] = *(const i32x4*)&lds[bB0 + (bcol_ + j * 16) * 64 + xs16];
    i32x4 a[4];
#pragma unroll
    for (int i = 0; i < 4; ++i)
      a[i] = *(const i32x4*)&lds[bA0 + (arow + i * 16) * 64 + xs16];
    if (MODE >= 1) stage_region(lds, cur ^ 1, 0, 1, kt + 1, A8, B8, brow, bcol, tid);
    __builtin_amdgcn_s_barrier();
    __builtin_amdgcn_s_setprio(1);
#pragma unroll
    for (int i = 0; i < 4; ++i)
#pragma unroll
      for (int j = 0; j < 4; ++j)
        acc[i][j] = __builtin_amdgcn_mfma_i32_16x16x64_i8(a[i], b[j], acc[i][j], 0, 0, 0);
    __builtin_amdgcn_s_setprio(0);
    __builtin_amdgcn_s_barrier();
  }

  // ---- phase (0,1): A.k0 rows 4-7 (b reused); stage B of kt+1.k1 ----
  {
    i32x4 a[4];
#pragma unroll
    for (int i = 0; i < 4; ++i)
      a[i] = *(const i32x4*)&lds[bA0 + (arow + (4 + i) * 16) * 64 + xs16];
    if (MODE >= 1) stage_region(lds, cur ^ 1, 1, 1, kt + 1, A8, B8, brow, bcol, tid);
    __builtin_amdgcn_s_barrier();
    __builtin_amdgcn_s_setprio(1);
#pragma unroll
    for (int i = 0; i < 4; ++i)
#pragma unroll
      for (int j = 0; j < 4; ++j)
        acc[4 + i][j] = __builtin_amdgcn_mfma_i32_16x16x64_i8(a[i], b[j], acc[4 + i][j], 0, 0, 0);
    __builtin_amdgcn_s_setprio(0);
    __builtin_amdgcn_s_barrier();
  }

  // ---- phase (1,0): read B.k1 + A.k1 rows 0-3; stage A of kt+2.k0 ----
  // (buf.k0 reads finished last phase -> safe to overwrite: issue is after
  //  that phase's end barrier, and every wave drained lgkm before its MFMA.)
  {
#pragma unroll
    for (int j = 0; j < 4; ++j)
      b[j] = *(const i32x4*)&lds[bB1 + (bcol_ + j * 16) * 64 + xs16];
    i32x4 a[4];
#pragma unroll
    for (int i = 0; i < 4; ++i)
      a[i] = *(const i32x4*)&lds[bA1 + (arow + i * 16) * 64 + xs16];
    if (MODE == 2) stage_region(lds, cur, 0, 0, kt + 2, A8, B8, brow, bcol, tid);
    __builtin_amdgcn_s_barrier();
    __builtin_amdgcn_s_setprio(1);
#pragma unroll
    for (int i = 0; i < 4; ++i)
#pragma unroll
      for (int j = 0; j < 4; ++j)
        acc[i][j] = __builtin_amdgcn_mfma_i32_16x16x64_i8(a[i], b[j], acc[i][j], 0, 0, 0);
    __builtin_amdgcn_s_setprio(0);
    __builtin_amdgcn_s_barrier();
  }

  // ---- phase (1,1): A.k1 rows 4-7; stage B of kt+2.k0; K-tile checkpoint ----
  {
    i32x4 a[4];
#pragma unroll
    for (int i = 0; i < 4; ++i)
      a[i] = *(const i32x4*)&lds[bA1 + (arow + (4 + i) * 16) * 64 + xs16];
    if (MODE == 2) stage_region(lds, cur, 1, 0, kt + 2, A8, B8, brow, bcol, tid);
    __builtin_amdgcn_s_barrier();
    __builtin_amdgcn_s_setprio(1);
#pragma unroll
    for (int i = 0; i < 4; ++i)
#pragma unroll
      for (int j = 0; j < 4; ++j)
        acc[4 + i][j] = __builtin_amdgcn_mfma_i32_16x16x64_i8(a[i], b[j], acc[4 + i][j], 0, 0, 0);
    __builtin_amdgcn_s_setprio(0);
    // Once-per-K-tile counted checkpoint: guarantees kt+1 fully landed;
    // kt+2.k0's 4 loads stay in flight (never vmcnt(0) in steady state).
    if (MODE == 2)      asm volatile("s_waitcnt vmcnt(4)" ::: "memory");
    else if (MODE == 1) asm volatile("s_waitcnt vmcnt(0)" ::: "memory");
    __builtin_amdgcn_s_barrier();
  }
}

__global__ __launch_bounds__(512, 2) void w8a8_gemm_kernel(
    const int8_t* __restrict__ A8,            // [N_TOK][K_DIM]
    const int8_t* __restrict__ B8,            // [M_DIM][K_DIM]
    const float* __restrict__ input_scale,    // [N_TOK]
    const float* __restrict__ dequant_scale,  // [M_DIM]
    const float* __restrict__ bias,           // [M_DIM]
    float* __restrict__ out)                  // [N_TOK][M_DIM] f32
{
  __shared__ int8_t lds[131072];              // 128 KiB -> 1 block/CU

  const int tid  = threadIdx.x;
  const int lane = tid & 63;
  const int wid  = tid >> 6;      // 0..7
  const int wr   = wid >> 2;      // 0..1 -> 128-row half
  const int wc   = wid & 3;       // 0..3 -> 64-col slice
  const int lr   = lane & 15;
  const int lg   = lane >> 4;
  const int xs16 = ((lg ^ (lr & 3)) << 4);   // swizzled 16-B slot for frag reads

  // XCD-aware swizzle (768 % 8 == 0 -> bijective) + GROUP_M=4 chunking
  int bid = blockIdx.x;
  int w_  = (bid & 7) * (NWG / 8) + (bid >> 3);
  const int width = 4 * GRID_N;   // 192
  int gid = w_ / width, rem = w_ % width;
  int bm = gid * 4 + (rem & 3);
  int bn = rem >> 2;
  const int brow = bm * BM;
  const int bcol = bn * BN;

  i32x4 acc[8][4] = {};

  // Prologue: kt0.k0, kt0.k1, kt1.k0 (12 loads); wait for kt0 (8 oldest).
  stage_region(lds, 0, 0, 0, 0, A8, B8, brow, bcol, tid);
  stage_region(lds, 0, 1, 0, 0, A8, B8, brow, bcol, tid);
  stage_region(lds, 0, 0, 1, 0, A8, B8, brow, bcol, tid);
  stage_region(lds, 0, 1, 1, 0, A8, B8, brow, bcol, tid);
  stage_region(lds, 1, 0, 0, 1, A8, B8, brow, bcol, tid);
  stage_region(lds, 1, 1, 0, 1, A8, B8, brow, bcol, tid);
  asm volatile("s_waitcnt vmcnt(4)" ::: "memory");
  __builtin_amdgcn_s_barrier();

  for (int kt = 0; kt < KT - 2; ++kt)
    ktile<2>(kt, lds, A8, B8, brow, bcol, tid, wr, wc, lr, xs16, acc);
  ktile<1>(KT - 2, lds, A8, B8, brow, bcol, tid, wr, wc, lr, xs16, acc);
  ktile<0>(KT - 1, lds, A8, B8, brow, bcol, tid, wr, wc, lr, xs16, acc);

  // Epilogue: out[n][m] = acc * is[n] * ds[m] + bias[m]
  // C/D 16x16 layout: col = lane&15, row = (lane>>4)*4 + reg
  const int orow = brow + wr * 128;
  const int ocol = bcol + wc * 64 + lr;
#pragma unroll
  for (int j = 0; j < 4; ++j) {
    const int m = ocol + j * 16;
    const float dsc = dequant_scale[m];
    const float bs  = bias[m];
#pragma unroll
    for (int fi = 0; fi < 8; ++fi) {
#pragma unroll
      for (int r = 0; r < 4; ++r) {
        const int n = orow + fi * 16 + lg * 4 + r;
        out[(size_t)n * M_DIM + m] = (float)acc[fi][j][r] * input_scale[n] * dsc + bs;
      }
    }
  }
}

extern "C" void kernel_launch(void* const* d_in, const int* in_sizes, int n_in,
                              void* d_out, int out_size, void* d_ws, size_t ws_size,
                              hipStream_t stream) {
  const int*   x             = (const int*)d_in[0];     // [N,K] int32 (values fit i8)
  const int*   w             = (const int*)d_in[1];     // [M,K] int32
  const float* input_scale   = (const float*)d_in[2];   // [N]
  const float* dequant_scale = (const float*)d_in[3];   // [M]
  const float* bias          = (const float*)d_in[4];   // [M]
  float*       out           = (float*)d_out;           // [N,M] f32

  int8_t* x8 = (int8_t*)d_ws;                           // 16 MB
  int8_t* w8 = x8 + (size_t)N_TOK * K_DIM;              // 48 MB, contiguous

  pack_i8_kernel<<<4096, 256, 0, stream>>>(x, w, (int*)d_ws);
  w8a8_gemm_kernel<<<NWG, 512, 0, stream>>>(x8, w8, input_scale, dequant_scale,
                                            bias, out);
}

// Round 3
// 560.839 us; speedup vs baseline: 1.0881x; 1.0126x over previous
//
#include <hip/hip_runtime.h>
#include <cstdint>
#include <cstddef>

// Problem constants (from reference)
#define N_TOK 4096
#define K_DIM 4096
#define M_DIM 12288

using i32x4 = __attribute__((ext_vector_type(4))) int;

// ---------------- pack int32 -> int8 (fully coalesced) ----------------
constexpr long GROUPS_X     = (long)N_TOK * K_DIM / 4;               // 4,194,304
constexpr long GROUPS_TOTAL = ((long)N_TOK + M_DIM) * K_DIM / 4;     // 16,777,216

__global__ __launch_bounds__(256) void pack_i8_kernel(
    const int* __restrict__ x, const int* __restrict__ w, int* __restrict__ out8)
{
  const long stride = (long)gridDim.x * 256;
  for (long g = (long)blockIdx.x * 256 + threadIdx.x; g < GROUPS_TOTAL; g += stride) {
    const int* src = (g < GROUPS_X) ? (x + g * 4) : (w + (g - GROUPS_X) * 4);
    i32x4 v = *(const i32x4*)src;
    out8[g] = (v.x & 0xff) | ((v.y & 0xff) << 8) | ((v.z & 0xff) << 16) | (v.w << 24);
  }
}

// ---------------- i8 GEMM, 256x256 8-phase pipeline ----------------
#define BM 256
#define BN 256
#define KT 32                        // K_DIM / 128 bytes per K-tile
#define GRID_M (N_TOK / BM)          // 16
#define GRID_N (M_DIM / BN)          // 48
#define NWG (GRID_M * GRID_N)        // 768

__device__ __forceinline__ void load_lds16(const void* g, void* l) {
  __builtin_amdgcn_global_load_lds(
      (const __attribute__((address_space(1))) void*)g,
      (__attribute__((address_space(3))) void*)l, 16, 0, 0);
}

// LDS map: region(buf, ab, s) = (buf*4 + ab*2 + s) * 16384 bytes.
// Each region: [256 rows][64 B] row-major, 16 KiB. Total 128 KiB.
// Swizzle (both-sides involution): 16-B slot' = slot ^ ((row >> 1) & 3).
// Rationale: fragment reads have row = 16t + (lane&15), slot = lane>>4.
// XOR with (row>>1)&3 makes each 16-lane quarter-wave hit all 8 bank-span
// positions (32 banks) exactly twice -> balanced, no structural conflict.
// (The previous row&3 variant collapsed to 4 spans -> 4 extra cyc/read,
// exactly the measured 1.887e7 conflict cycles.)

// Stage one region (16 KiB) = 2 global_load_lds per thread (512 threads).
__device__ __forceinline__ void stage_region(
    int8_t* lds, int buf, int ab, int s, int ktarg,
    const int8_t* A8, const int8_t* B8, int brow, int bcol, int tid)
{
  const int8_t* gbase = ab ? (B8 + (size_t)bcol * K_DIM)
                           : (A8 + (size_t)brow * K_DIM);
  const int lb = (buf * 4 + ab * 2 + s) * 16384;
  const int gk = ktarg * 128 + s * 64;
#pragma unroll
  for (int p = 0; p < 2; ++p) {
    int c = p * 512 + tid;           // 0..1023 chunks of 16 B
    int row  = c >> 2;
    int slot = (c & 3) ^ ((row >> 1) & 3);  // inverse-swizzled GLOBAL source
    load_lds16(gbase + (size_t)row * K_DIM + gk + slot * 16,
               lds + lb + c * 16);   // LINEAR LDS dest (HW requirement)
  }
}

// One K-tile = 4 phases. MODE: 2 = stage kt+1.k1 and kt+2.k0 (steady),
// 1 = stage only kt+1.k1 (kt == KT-2), 0 = no staging (last K-tile).
template <int MODE>
__device__ __forceinline__ void ktile(
    int kt, int8_t* lds, const int8_t* A8, const int8_t* B8,
    int brow, int bcol, int tid, int wr, int wc, int lr, int xs16,
    i32x4 (&acc)[8][4])
{
  const int cur = kt & 1;
  const int bA0 = (cur * 4 + 0) * 16384;
  const int bA1 = (cur * 4 + 1) * 16384;
  const int bB0 = (cur * 4 + 2) * 16384;
  const int bB1 = (cur * 4 + 3) * 16384;
  const int arow = wr * 128 + lr;    // A frag base row within tile
  const int bcol_ = wc * 64 + lr;    // B frag base row (output col) within tile

  i32x4 b[4];

  // ---- phase (s=0, h=0): read B.k0 + A.k0 rows 0-3; stage A of kt+1.k1 ----
  {
#pragma unroll
    for (int j = 0; j < 4; ++j)
      b[j] = *(const i32x4*)&lds[bB0 + (bcol_ + j * 16) * 64 + xs16];
    i32x4 a[4];
#pragma unroll
    for (int i = 0; i < 4; ++i)
      a[i] = *(const i32x4*)&lds[bA0 + (arow + i * 16) * 64 + xs16];
    if (MODE >= 1) stage_region(lds, cur ^ 1, 0, 1, kt + 1, A8, B8, brow, bcol, tid);
    __builtin_amdgcn_s_barrier();
    __builtin_amdgcn_s_setprio(1);
#pragma unroll
    for (int i = 0; i < 4; ++i)
#pragma unroll
      for (int j = 0; j < 4; ++j)
        acc[i][j] = __builtin_amdgcn_mfma_i32_16x16x64_i8(a[i], b[j], acc[i][j], 0, 0, 0);
    __builtin_amdgcn_s_setprio(0);
    __builtin_amdgcn_s_barrier();
  }

  // ---- phase (0,1): A.k0 rows 4-7 (b reused); stage B of kt+1.k1 ----
  {
    i32x4 a[4];
#pragma unroll
    for (int i = 0; i < 4; ++i)
      a[i] = *(const i32x4*)&lds[bA0 + (arow + (4 + i) * 16) * 64 + xs16];
    if (MODE >= 1) stage_region(lds, cur ^ 1, 1, 1, kt + 1, A8, B8, brow, bcol, tid);
    __builtin_amdgcn_s_barrier();
    __builtin_amdgcn_s_setprio(1);
#pragma unroll
    for (int i = 0; i < 4; ++i)
#pragma unroll
      for (int j = 0; j < 4; ++j)
        acc[4 + i][j] = __builtin_amdgcn_mfma_i32_16x16x64_i8(a[i], b[j], acc[4 + i][j], 0, 0, 0);
    __builtin_amdgcn_s_setprio(0);
    __builtin_amdgcn_s_barrier();
  }

  // ---- phase (1,0): read B.k1 + A.k1 rows 0-3; stage A of kt+2.k0 ----
  {
#pragma unroll
    for (int j = 0; j < 4; ++j)
      b[j] = *(const i32x4*)&lds[bB1 + (bcol_ + j * 16) * 64 + xs16];
    i32x4 a[4];
#pragma unroll
    for (int i = 0; i < 4; ++i)
      a[i] = *(const i32x4*)&lds[bA1 + (arow + i * 16) * 64 + xs16];
    if (MODE == 2) stage_region(lds, cur, 0, 0, kt + 2, A8, B8, brow, bcol, tid);
    __builtin_amdgcn_s_barrier();
    __builtin_amdgcn_s_setprio(1);
#pragma unroll
    for (int i = 0; i < 4; ++i)
#pragma unroll
      for (int j = 0; j < 4; ++j)
        acc[i][j] = __builtin_amdgcn_mfma_i32_16x16x64_i8(a[i], b[j], acc[i][j], 0, 0, 0);
    __builtin_amdgcn_s_setprio(0);
    __builtin_amdgcn_s_barrier();
  }

  // ---- phase (1,1): A.k1 rows 4-7; stage B of kt+2.k0; K-tile checkpoint ----
  {
    i32x4 a[4];
#pragma unroll
    for (int i = 0; i < 4; ++i)
      a[i] = *(const i32x4*)&lds[bA1 + (arow + (4 + i) * 16) * 64 + xs16];
    if (MODE == 2) stage_region(lds, cur, 1, 0, kt + 2, A8, B8, brow, bcol, tid);
    __builtin_amdgcn_s_barrier();
    __builtin_amdgcn_s_setprio(1);
#pragma unroll
    for (int i = 0; i < 4; ++i)
#pragma unroll
      for (int j = 0; j < 4; ++j)
        acc[4 + i][j] = __builtin_amdgcn_mfma_i32_16x16x64_i8(a[i], b[j], acc[4 + i][j], 0, 0, 0);
    __builtin_amdgcn_s_setprio(0);
    // Once-per-K-tile counted checkpoint: guarantees kt+1 fully landed;
    // kt+2.k0's 4 loads stay in flight (never vmcnt(0) in steady state).
    if (MODE == 2)      asm volatile("s_waitcnt vmcnt(4)" ::: "memory");
    else if (MODE == 1) asm volatile("s_waitcnt vmcnt(0)" ::: "memory");
    __builtin_amdgcn_s_barrier();
  }
}

__global__ __launch_bounds__(512, 2) void w8a8_gemm_kernel(
    const int8_t* __restrict__ A8,            // [N_TOK][K_DIM]
    const int8_t* __restrict__ B8,            // [M_DIM][K_DIM]
    const float* __restrict__ input_scale,    // [N_TOK]
    const float* __restrict__ dequant_scale,  // [M_DIM]
    const float* __restrict__ bias,           // [M_DIM]
    float* __restrict__ out)                  // [N_TOK][M_DIM] f32
{
  __shared__ int8_t lds[131072];              // 128 KiB -> 1 block/CU

  const int tid  = threadIdx.x;
  const int lane = tid & 63;
  const int wid  = tid >> 6;      // 0..7
  const int wr   = wid >> 2;      // 0..1 -> 128-row half
  const int wc   = wid & 3;       // 0..3 -> 64-col slice
  const int lr   = lane & 15;
  const int lg   = lane >> 4;
  // Swizzled 16-B slot for frag reads: row = 16t + lr -> (row>>1)&3 = (lr>>1)&3
  const int xs16 = ((lg ^ ((lr >> 1) & 3)) << 4);

  // XCD-aware swizzle (768 % 8 == 0 -> bijective) + GROUP_M=4 chunking
  int bid = blockIdx.x;
  int w_  = (bid & 7) * (NWG / 8) + (bid >> 3);
  const int width = 4 * GRID_N;   // 192
  int gid = w_ / width, rem = w_ % width;
  int bm = gid * 4 + (rem & 3);
  int bn = rem >> 2;
  const int brow = bm * BM;
  const int bcol = bn * BN;

  i32x4 acc[8][4] = {};

  // Prologue: kt0.k0, kt0.k1, kt1.k0 (12 loads); wait for kt0 (8 oldest).
  stage_region(lds, 0, 0, 0, 0, A8, B8, brow, bcol, tid);
  stage_region(lds, 0, 1, 0, 0, A8, B8, brow, bcol, tid);
  stage_region(lds, 0, 0, 1, 0, A8, B8, brow, bcol, tid);
  stage_region(lds, 0, 1, 1, 0, A8, B8, brow, bcol, tid);
  stage_region(lds, 1, 0, 0, 1, A8, B8, brow, bcol, tid);
  stage_region(lds, 1, 1, 0, 1, A8, B8, brow, bcol, tid);
  asm volatile("s_waitcnt vmcnt(4)" ::: "memory");
  __builtin_amdgcn_s_barrier();

  for (int kt = 0; kt < KT - 2; ++kt)
    ktile<2>(kt, lds, A8, B8, brow, bcol, tid, wr, wc, lr, xs16, acc);
  ktile<1>(KT - 2, lds, A8, B8, brow, bcol, tid, wr, wc, lr, xs16, acc);
  ktile<0>(KT - 1, lds, A8, B8, brow, bcol, tid, wr, wc, lr, xs16, acc);

  // Epilogue: out[n][m] = acc * is[n] * ds[m] + bias[m]
  // C/D 16x16 layout: col = lane&15, row = (lane>>4)*4 + reg
  const int orow = brow + wr * 128;
  const int ocol = bcol + wc * 64 + lr;
#pragma unroll
  for (int j = 0; j < 4; ++j) {
    const int m = ocol + j * 16;
    const float dsc = dequant_scale[m];
    const float bs  = bias[m];
#pragma unroll
    for (int fi = 0; fi < 8; ++fi) {
#pragma unroll
      for (int r = 0; r < 4; ++r) {
        const int n = orow + fi * 16 + lg * 4 + r;
        out[(size_t)n * M_DIM + m] = (float)acc[fi][j][r] * input_scale[n] * dsc + bs;
      }
    }
  }
}

extern "C" void kernel_launch(void* const* d_in, const int* in_sizes, int n_in,
                              void* d_out, int out_size, void* d_ws, size_t ws_size,
                              hipStream_t stream) {
  const int*   x             = (const int*)d_in[0];     // [N,K] int32 (values fit i8)
  const int*   w             = (const int*)d_in[1];     // [M,K] int32
  const float* input_scale   = (const float*)d_in[2];   // [N]
  const float* dequant_scale = (const float*)d_in[3];   // [M]
  const float* bias          = (const float*)d_in[4];   // [M]
  float*       out           = (float*)d_out;           // [N,M] f32

  int8_t* x8 = (int8_t*)d_ws;                           // 16 MB
  int8_t* w8 = x8 + (size_t)N_TOK * K_DIM;              // 48 MB, contiguous

  pack_i8_kernel<<<4096, 256, 0, stream>>>(x, w, (int*)d_ws);
  w8a8_gemm_kernel<<<NWG, 512, 0, stream>>>(x8, w8, input_scale, dequant_scale,
                                            bias, out);
}